// Round 6
// baseline (221.299 us; speedup 1.0000x reference)
//
#include <hip/hip_runtime.h>
#include <hip/hip_bf16.h>
#include <cstdint>

typedef __bf16 bf16;
typedef __attribute__((ext_vector_type(8))) __bf16 bf16x8;
typedef __attribute__((ext_vector_type(4))) __bf16 bf16x4;
typedef __attribute__((ext_vector_type(4))) float f32x4;

#define MFMA16 __builtin_amdgcn_mfma_f32_16x16x32_bf16
#define MASKV (-1e30f)

static constexpr int Lq  = 2048;
static constexpr int BKt = 64;    // keys per tile

__device__ __forceinline__ void async_load16(const void* g, void* l) {
  __builtin_amdgcn_global_load_lds(
      (__attribute__((address_space(1))) void*)g,
      (__attribute__((address_space(3))) void*)l, 16, 0, 0);
}

// ---------------------------------------------------------------------------
// fp32 -> bf16 conversion of all inputs
// ---------------------------------------------------------------------------
__global__ void convert_all(const float* __restrict__ q, const float* __restrict__ k,
                            const float* __restrict__ v, const float* __restrict__ wq,
                            const float* __restrict__ wk, const float* __restrict__ wv,
                            const float* __restrict__ fc, const float* __restrict__ E,
                            bf16* q_bf, bf16* k_bf, bf16* v_bf, bf16* wq_bf,
                            bf16* wk_bf, bf16* wv_bf, bf16* fc_bf, bf16* E_bf)
{
  int i = blockIdx.x * blockDim.x + threadIdx.x;   // vec4 index
  const float* src; bf16* dst; int rel;
  if      (i < 524288)  { src = q;  dst = q_bf;  rel = i; }
  else if (i < 1048576) { src = k;  dst = k_bf;  rel = i - 524288; }
  else if (i < 1572864) { src = v;  dst = v_bf;  rel = i - 1048576; }
  else if (i < 1638400) { src = wq; dst = wq_bf; rel = i - 1572864; }
  else if (i < 1703936) { src = wk; dst = wk_bf; rel = i - 1638400; }
  else if (i < 1769472) { src = wv; dst = wv_bf; rel = i - 1703936; }
  else if (i < 1835008) { src = fc; dst = fc_bf; rel = i - 1769472; }
  else if (i < 1867776) { src = E;  dst = E_bf;  rel = i - 1835008; }
  else return;
  float4 x = *(const float4*)(src + (size_t)rel * 4);
  bf16x4 o;
  o[0] = (bf16)x.x; o[1] = (bf16)x.y; o[2] = (bf16)x.z; o[3] = (bf16)x.w;
  *(bf16x4*)(dst + (size_t)rel * 4) = o;
}

__global__ void zero_s(float* __restrict__ s_buf) {
  int i = blockIdx.x * blockDim.x + threadIdx.x;   // float4 index, 8192 total
  if (i < 8192) ((float4*)s_buf)[i] = make_float4(0.f, 0.f, 0.f, 0.f);
}

// ---------------------------------------------------------------------------
// Generic 128x128-tile bf16 GEMM, C[i][j] = sum_k A[i][k]*B[j][k] + bias
// MODE 0: C bf16 (B,H,L,DH) ; MODE 2: C bf16 (B,H,DH,L), bias[i] ; MODE 3: fp32
// ---------------------------------------------------------------------------
template<int MODE>
__global__ __launch_bounds__(256, 2)
void gemm512(const bf16* __restrict__ A, const bf16* __restrict__ Bm,
             const float* __restrict__ bias, void* __restrict__ Cv)
{
  __shared__ __align__(16) char lA[16384];
  __shared__ __align__(16) char lB[16384];
  const int tid = threadIdx.x, lane = tid & 63, wv = tid >> 6;
  const int wr = wv >> 1, wc = wv & 1;
  const int tm = blockIdx.x, tn = blockIdx.y;

  f32x4 acc[4][4];
#pragma unroll
  for (int m = 0; m < 4; ++m)
#pragma unroll
    for (int n = 0; n < 4; ++n) acc[m][n] = (f32x4){0.f, 0.f, 0.f, 0.f};

  for (int k0 = 0; k0 < 512; k0 += 64) {
    __syncthreads();
#pragma unroll
    for (int it = 0; it < 4; ++it) {
      int slot = it * 256 + wv * 64 + lane;
      int row = slot >> 3, c = slot & 7;
      int gk = k0 + ((c ^ (row & 7)) * 8);
      async_load16(A  + (size_t)(tm * 128 + row) * 512 + gk, lA + (it * 256 + wv * 64) * 16);
      async_load16(Bm + (size_t)(tn * 128 + row) * 512 + gk, lB + (it * 256 + wv * 64) * 16);
    }
    __syncthreads();
#pragma unroll
    for (int kc = 0; kc < 2; ++kc) {
      bf16x8 af[4], bfr[4];
#pragma unroll
      for (int m = 0; m < 4; ++m) {
        int row = wr * 64 + m * 16 + (lane & 15);
        int ch = ((lane >> 4) + kc * 4) ^ (row & 7);
        af[m] = *(const bf16x8*)(lA + row * 128 + ch * 16);
      }
#pragma unroll
      for (int n = 0; n < 4; ++n) {
        int row = wc * 64 + n * 16 + (lane & 15);
        int ch = ((lane >> 4) + kc * 4) ^ (row & 7);
        bfr[n] = *(const bf16x8*)(lB + row * 128 + ch * 16);
      }
#pragma unroll
      for (int m = 0; m < 4; ++m)
#pragma unroll
        for (int n = 0; n < 4; ++n)
          acc[m][n] = MFMA16(af[m], bfr[n], acc[m][n], 0, 0, 0);
    }
  }

#pragma unroll
  for (int m = 0; m < 4; ++m)
#pragma unroll
    for (int n = 0; n < 4; ++n)
#pragma unroll
      for (int r = 0; r < 4; ++r) {
        int gi = tm * 128 + wr * 64 + m * 16 + 4 * (lane >> 4) + r;
        int gj = tn * 128 + wc * 64 + n * 16 + (lane & 15);
        float vv = acc[m][n][r] + ((MODE == 2) ? bias[gi] : bias[gj]);
        if (MODE == 3) {
          ((float*)Cv)[(size_t)gi * 512 + gj] = vv;
        } else if (MODE == 2) {
          int h = gi >> 6, dh = gi & 63, b = gj >> 11, l = gj & 2047;
          ((bf16*)Cv)[((size_t)((b * 8 + h) * 64 + dh)) * 2048 + l] = (bf16)vv;
        } else {
          int b = gi >> 11, l = gi & 2047, h = gj >> 6, dh = gj & 63;
          ((bf16*)Cv)[((size_t)((b * 8 + h) * 2048 + l)) * 64 + dh] = (bf16)vv;
        }
      }
}

// ---------------------------------------------------------------------------
// Attention helpers
// ---------------------------------------------------------------------------
__device__ __forceinline__ void stage_k(const bf16* __restrict__ kb, int j0,
                                        char* dst, int tid) {
#pragma unroll
  for (int it = 0; it < 2; ++it) {
    int slot = it * 256 + tid;
    int row = slot >> 3, c = slot & 7;
    async_load16(kb + (size_t)(j0 + row) * 64 + ((c ^ (row & 7)) * 8), dst + slot * 16);
  }
}
__device__ __forceinline__ void stage_v(const bf16* __restrict__ vb, int j0,
                                        char* dst, int tid) {
#pragma unroll
  for (int it = 0; it < 2; ++it) {
    int slot = it * 256 + tid;
    int row = slot >> 3, c = slot & 7;
    async_load16(vb + (size_t)row * Lq + j0 + ((c ^ (row & 7)) * 8), dst + slot * 16);
  }
}

// ---------------------------------------------------------------------------
// Logits for one 16q x 64k tile: acc_s = (QK + Srel)/8, masked -> MASKV.
// T diagonal gather done IN-REGISTER via ds_bpermute (__shfl):
//   source lane = (lane&48)|(ct&15), frames {3-cf, 4-cf}, select (4g+r)>b.
// ---------------------------------------------------------------------------
__device__ __forceinline__ void attn_logits_sh(
    int i0, int j0, int wvx, int lane,
    const bf16x8 qf0, const bf16x8 qf1,
    const bf16* __restrict__ Ebf, const char* lk, f32x4 acc_s[4])
{
  const int rbase = i0 + wvx * 16 - j0 - 63;
  f32x4 acc_t[5];
#pragma unroll
  for (int cf = 0; cf < 5; ++cf) {
    int r = rbase + cf * 16 + (lane & 15);
    int re = 2047 - r; re = re < 0 ? 0 : (re > 2047 ? 2047 : re);
    const bf16* ep = Ebf + (size_t)re * 64 + (lane >> 4) * 8;
    f32x4 a = (f32x4){0.f, 0.f, 0.f, 0.f};
    a = MFMA16(qf0, *(const bf16x8*)ep, a, 0, 0, 0);
    a = MFMA16(qf1, *(const bf16x8*)(ep + 32), a, 0, 0, 0);
    acc_t[cf] = a;
  }
#pragma unroll
  for (int cf = 0; cf < 4; ++cf) {
    int key = cf * 16 + (lane & 15);
    int c0 = (lane >> 4) ^ (key & 7);
    int c1 = ((lane >> 4) + 4) ^ (key & 7);
    f32x4 a = (f32x4){0.f, 0.f, 0.f, 0.f};
    a = MFMA16(qf0, *(const bf16x8*)(lk + key * 128 + c0 * 16), a, 0, 0, 0);
    a = MFMA16(qf1, *(const bf16x8*)(lk + key * 128 + c1 * 16), a, 0, 0, 0);
    acc_s[cf] = a;
  }
  const int g = lane >> 4, b = lane & 15;
#pragma unroll
  for (int r = 0; r < 4; ++r) {
    const int qw  = 4 * g + r;
    const int sl  = (lane & 48) | ((63 + qw - b) & 15);
    const bool hi = qw > b;
#pragma unroll
    for (int cf = 0; cf < 4; ++cf) {
      float vhi = __shfl(acc_t[4 - cf][r], sl);
      float vlo = __shfl(acc_t[3 - cf][r], sl);
      float t = hi ? vhi : vlo;
      float vv = (acc_s[cf][r] + t) * 0.125f;
      if (j0 + cf * 16 + b > i0 + wvx * 16 + qw) vv = MASKV;
      acc_s[cf][r] = vv;
    }
  }
}

// ---------------------------------------------------------------------------
// PASS 1: row sums of exp(logits) via atomicAdd into s_buf[bh*2048 + row].
// Grid 2304 = 8 xcd * 2 bh * 144 chunks (<=4 j-tiles each), heavy qt first.
// ---------------------------------------------------------------------------
__global__ __launch_bounds__(256, 5)
void pass1_sums(const bf16* __restrict__ qh, const bf16* __restrict__ kh,
                const bf16* __restrict__ Ebf, float* __restrict__ s_buf)
{
  __shared__ __align__(16) char lds_k[2][64 * 128];
  const int tid = threadIdx.x, lane = tid & 63, wvx = tid >> 6;
  const int n    = blockIdx.x;
  const int xcd  = n & 7;
  const int r0   = n >> 3;               // 0..287
  const int bh   = 2 * xcd + (r0 & 1);
  int rem = r0 >> 1, qt = 31, f = 0;     // heavy qt first
#pragma unroll 1
  for (int q = 31; q >= 0; --q) {
    int c = (q >> 2) + 1;
    if (rem < c) { qt = q; f = rem; break; }
    rem -= c;
  }
  const int jbeg = f * 4;
  const int jend = (jbeg + 4 < qt + 1) ? jbeg + 4 : qt + 1;
  const int i0 = qt * 64;

  const bf16* qb = qh + (size_t)bh * Lq * 64;
  const bf16* kb = kh + (size_t)bh * Lq * 64;

  const int qrow = i0 + wvx * 16 + (lane & 15);
  const bf16x8 qf0 = *(const bf16x8*)(qb + (size_t)qrow * 64 + (lane >> 4) * 8);
  const bf16x8 qf1 = *(const bf16x8*)(qb + (size_t)qrow * 64 + 32 + (lane >> 4) * 8);

  f32x4 acc_s[4];
  float s_acc[4] = {0.f, 0.f, 0.f, 0.f};

  stage_k(kb, jbeg * BKt, lds_k[0], tid);
  __syncthreads();
  for (int jt = jbeg; jt < jend; ++jt) {
    const int lt = (jt - jbeg) & 1;
    if (jt + 1 < jend) stage_k(kb, (jt + 1) * BKt, lds_k[lt ^ 1], tid);
    attn_logits_sh(i0, jt * BKt, wvx, lane, qf0, qf1, Ebf, lds_k[lt], acc_s);
#pragma unroll
    for (int r = 0; r < 4; ++r) {
#pragma unroll
      for (int cf = 0; cf < 4; ++cf) s_acc[r] += __expf(acc_s[cf][r]);
    }
    __syncthreads();
  }
#pragma unroll
  for (int r = 0; r < 4; ++r) {
    float s = s_acc[r];
    for (int d = 1; d < 16; d <<= 1) s += __shfl_xor(s, d);
    if ((lane & 15) == 0)
      atomicAdd(&s_buf[bh * Lq + i0 + wvx * 16 + 4 * (lane >> 4) + r], s);
  }
}

// ---------------------------------------------------------------------------
// MAIN: grid 4096 = 8 xcd * 2 bh * 32 qt * 8 chunks (256 cols each).
// Compute chunks (jbeg<=qt): normalized attn write + O partial -> O_slots.
// Past-diagonal j-tiles inside the chunk get zero-filled; pure-masked
// chunks are plain zero writers.
// ---------------------------------------------------------------------------
__global__ __launch_bounds__(256, 4)
void attn_main(const bf16* __restrict__ qh, const bf16* __restrict__ kh,
               const bf16* __restrict__ vt, const bf16* __restrict__ Ebf,
               const float* __restrict__ s_buf, float* __restrict__ attn_out,
               float* __restrict__ O_slots)
{
  __shared__ __align__(16) char lds_k[2][64 * 128];
  __shared__ __align__(16) char lds_v[2][64 * 128];
  __shared__ __align__(16) char lds_p[4][16 * 64 * 2];

  const int tid = threadIdx.x, lane = tid & 63, wvx = tid >> 6;
  const int n    = blockIdx.x;
  const int xcd  = n & 7;
  const int r0   = n >> 3;               // 0..511
  const int bh   = 2 * xcd + (r0 & 1);
  const int u    = r0 >> 1;              // 0..255
  const int f    = u >> 5;               // chunk 0..7
  const int qt   = u & 31;
  const int i0   = qt * 64;
  const int jbeg = f * 4;
  const int jend = (jbeg + 4 < qt + 1) ? jbeg + 4 : qt + 1;

  float* attn_b = attn_out + (size_t)bh * Lq * Lq;

  if (jbeg <= qt) {
    const bf16* qb = qh + (size_t)bh * Lq * 64;
    const bf16* kb = kh + (size_t)bh * Lq * 64;
    const bf16* vb = vt + (size_t)bh * 64 * Lq;
    bf16* pst = (bf16*)lds_p[wvx];

    const int qrow = i0 + wvx * 16 + (lane & 15);
    const bf16x8 qf0 = *(const bf16x8*)(qb + (size_t)qrow * 64 + (lane >> 4) * 8);
    const bf16x8 qf1 = *(const bf16x8*)(qb + (size_t)qrow * 64 + 32 + (lane >> 4) * 8);

    float inv_s[4];
#pragma unroll
    for (int r = 0; r < 4; ++r)
      inv_s[r] = 1.f / s_buf[bh * Lq + i0 + wvx * 16 + 4 * (lane >> 4) + r];

    f32x4 acc_s[4];
    f32x4 acc_o[4];
#pragma unroll
    for (int nn = 0; nn < 4; ++nn) acc_o[nn] = (f32x4){0.f, 0.f, 0.f, 0.f};

    stage_k(kb, jbeg * BKt, lds_k[0], tid);
    stage_v(vb, jbeg * BKt, lds_v[0], tid);
    __syncthreads();
    for (int jt = jbeg; jt < jend; ++jt) {
      const int j0 = jt * BKt;
      const int lt = (jt - jbeg) & 1;
      if (jt + 1 < jend) {
        stage_k(kb, j0 + BKt, lds_k[lt ^ 1], tid);
        stage_v(vb, j0 + BKt, lds_v[lt ^ 1], tid);
      }
      attn_logits_sh(i0, j0, wvx, lane, qf0, qf1, Ebf, lds_k[lt], acc_s);
      // normalized exp -> swizzled P strip (bf16)
#pragma unroll
      for (int cf = 0; cf < 4; ++cf) {
        int kl = cf * 16 + (lane & 15);
        int chs = kl >> 3;
#pragma unroll
        for (int r = 0; r < 4; ++r) {
          int qw = 4 * (lane >> 4) + r;
          float p = __expf(acc_s[cf][r]) * inv_s[r];
          pst[qw * 64 + ((chs ^ (qw & 7)) * 8) + (kl & 7)] = (bf16)p;
        }
      }
      asm volatile("s_waitcnt lgkmcnt(0)" ::: "memory");
      __builtin_amdgcn_sched_barrier(0);
      // attn write: 256B-contiguous per 8-lane group
#pragma unroll
      for (int it = 0; it < 2; ++it) {
        int qw = it * 8 + (lane >> 3);
        int c = lane & 7;
        bf16x8 pv = *(const bf16x8*)(pst + qw * 64 + ((c ^ (qw & 7)) * 8));
        float* dst = attn_b + (size_t)(i0 + wvx * 16 + qw) * Lq + j0 + c * 8;
        float4 f0, f1;
        f0.x = (float)pv[0]; f0.y = (float)pv[1]; f0.z = (float)pv[2]; f0.w = (float)pv[3];
        f1.x = (float)pv[4]; f1.y = (float)pv[5]; f1.z = (float)pv[6]; f1.w = (float)pv[7];
        *(float4*)dst = f0; *(float4*)(dst + 4) = f1;
      }
      // O += P.V (normalized)
#pragma unroll
      for (int kc = 0; kc < 2; ++kc) {
        int qa = lane & 15;
        int cha = (kc * 4 + (lane >> 4)) ^ (qa & 7);
        bf16x8 pf = *(const bf16x8*)(pst + qa * 64 + cha * 8);
#pragma unroll
        for (int nn = 0; nn < 4; ++nn) {
          int dh = nn * 16 + (lane & 15);
          int chv = (kc * 4 + (lane >> 4)) ^ (dh & 7);
          bf16x8 vf = *(const bf16x8*)(lds_v[lt] + dh * 128 + chv * 16);
          acc_o[nn] = MFMA16(pf, vf, acc_o[nn], 0, 0, 0);
        }
      }
      __syncthreads();
    }

    // O partial -> slot (fp32)
    float* oslot = O_slots + (size_t)(((bh * 32 + qt) * 8 + f)) * 4096;
#pragma unroll
    for (int nn = 0; nn < 4; ++nn)
#pragma unroll
      for (int r = 0; r < 4; ++r) {
        int row = wvx * 16 + 4 * (lane >> 4) + r;
        oslot[row * 64 + nn * 16 + (lane & 15)] = acc_o[nn][r];
      }
  }

  // zero-fill past-diagonal j-tiles of this chunk
  for (int jt = (jbeg > qt + 1 ? jbeg : qt + 1); jt < jbeg + 4; ++jt) {
    const int j0 = jt * BKt;
#pragma unroll
    for (int kk = 0; kk < 4; ++kk) {
      int idx = kk * 256 + tid;          // 0..1023 float4 slots in 64x64 tile
      int row = idx >> 4, c4 = idx & 15;
      float* p = attn_b + (size_t)(i0 + row) * Lq + j0 + c4 * 4;
      *(float4*)p = make_float4(0.f, 0.f, 0.f, 0.f);
    }
  }
}

// ---------------------------------------------------------------------------
// Combine O slots -> oh (bf16). Grid 512 = [bh][qt] strips.
// ---------------------------------------------------------------------------
__global__ void combine_o(const float* __restrict__ O_slots, bf16* __restrict__ oh)
{
  const int sid = blockIdx.x;            // 0..511
  const int bh = sid >> 5, qt = sid & 31;
  const int nch = (qt >> 2) + 1;
  const float* base = O_slots + (size_t)(bh * 32 + qt) * 8 * 4096;
  const int b = bh >> 3, h = bh & 7;
  for (int e4 = threadIdx.x; e4 < 1024; e4 += 256) {
    float4 s = make_float4(0.f, 0.f, 0.f, 0.f);
    for (int ff = 0; ff < nch; ++ff) {
      float4 x = *(const float4*)(base + ff * 4096 + e4 * 4);
      s.x += x.x; s.y += x.y; s.z += x.z; s.w += x.w;
    }
    int row = (e4 * 4) >> 6;
    int col = (e4 * 4) & 63;
    int ig = qt * 64 + row;
    bf16x4 o;
    o[0] = (bf16)s.x; o[1] = (bf16)s.y; o[2] = (bf16)s.z; o[3] = (bf16)s.w;
    *(bf16x4*)(oh + (size_t)(b * 2048 + ig) * 512 + h * 64 + col) = o;
  }
}

// ---------------------------------------------------------------------------
extern "C" void kernel_launch(void* const* d_in, const int* in_sizes, int n_in,
                              void* d_out, int out_size, void* d_ws, size_t ws_size,
                              hipStream_t stream) {
  const float* q    = (const float*)d_in[0];
  const float* k    = (const float*)d_in[1];
  const float* v    = (const float*)d_in[2];
  const float* wq   = (const float*)d_in[3];
  const float* wq_b = (const float*)d_in[4];
  const float* wk   = (const float*)d_in[5];
  const float* wk_b = (const float*)d_in[6];
  const float* wv   = (const float*)d_in[7];
  const float* wv_b = (const float*)d_in[8];
  const float* fc   = (const float*)d_in[9];
  const float* fc_b = (const float*)d_in[10];
  const float* E    = (const float*)d_in[11];

  if (ws_size < 98959360) return;  // layout below (~94.4 MiB); observed ws ~1.1 GB
  char* ws = (char*)d_ws;
  bf16*  q_bf    = (bf16*)(ws);
  bf16*  k_bf    = (bf16*)(ws + 4194304);
  bf16*  v_bf    = (bf16*)(ws + 8388608);
  bf16*  wq_bf   = (bf16*)(ws + 12582912);
  bf16*  wk_bf   = (bf16*)(ws + 13107200);
  bf16*  wv_bf   = (bf16*)(ws + 13631488);
  bf16*  fc_bf   = (bf16*)(ws + 14155776);
  bf16*  E_bf    = (bf16*)(ws + 14680064);
  float* s_buf   = (float*)(ws + 14942208);
  bf16*  qh_bf   = (bf16*)(ws + 15073280);
  bf16*  kh_bf   = (bf16*)(ws + 19267584);
  bf16*  vt_bf   = (bf16*)(ws + 23461888);
  bf16*  oh_bf   = (bf16*)(ws + 27656192);
  float* O_slots = (float*)(ws + 31850496);   // 64 MiB

  float* out_f  = (float*)d_out;
  float* attn_f = out_f + 2097152;

  convert_all<<<7296, 256, 0, stream>>>(q, k, v, wq, wk, wv, fc, E,
      q_bf, k_bf, v_bf, wq_bf, wk_bf, wv_bf, fc_bf, E_bf);
  zero_s<<<32, 256, 0, stream>>>(s_buf);
  gemm512<0><<<dim3(32, 4), 256, 0, stream>>>(q_bf, wq_bf, wq_b, qh_bf);
  gemm512<0><<<dim3(32, 4), 256, 0, stream>>>(k_bf, wk_bf, wk_b, kh_bf);
  gemm512<2><<<dim3(4, 32), 256, 0, stream>>>(wv_bf, v_bf, wv_b, vt_bf);
  pass1_sums<<<2304, 256, 0, stream>>>(qh_bf, kh_bf, E_bf, s_buf);
  attn_main<<<4096, 256, 0, stream>>>(qh_bf, kh_bf, vt_bf, E_bf,
                                      s_buf, attn_f, O_slots);
  combine_o<<<512, 256, 0, stream>>>(O_slots, oh_bf);
  gemm512<3><<<dim3(32, 4), 256, 0, stream>>>(oh_bf, fc_bf, fc_b, out_f);
}